// Round 6
// baseline (386.925 us; speedup 1.0000x reference)
//
#include <hip/hip_runtime.h>

// ---------- types ----------
typedef __attribute__((ext_vector_type(8))) short bf16x8;   // 8 bf16 in 4 VGPRs
typedef __attribute__((ext_vector_type(4))) short bf16x4;   // 4 bf16 in 2 VGPRs
typedef __attribute__((ext_vector_type(4))) float f32x4;    // MFMA C/D

#define MFMA32(a,b,c) __builtin_amdgcn_mfma_f32_16x16x32_bf16((a),(b),(c),0,0,0)
#define MFMA16(a,b,c) __builtin_amdgcn_mfma_f32_16x16x16bf16_1k((a),(b),(c),0,0,0)
#define LOG2E 1.44269504f

__device__ __forceinline__ unsigned short f2bf(float f) {
  unsigned int u = __float_as_uint(f);
  u += 0x7fffu + ((u >> 16) & 1u);      // round-to-nearest-even
  return (unsigned short)(u >> 16);
}

// async global->LDS, 16B per lane; LDS dest = wave-uniform base + lane*16
__device__ __forceinline__ void cp16(const void* g, void* l) {
  __builtin_amdgcn_global_load_lds((const __attribute__((address_space(1))) void*)g,
                                   (__attribute__((address_space(3))) void*)l, 16, 0, 0);
}

// ---------- fp32 -> bf16 (query, memory) + bias pre-transform, one launch ----
__global__ void conv_both(const float* __restrict__ q, const float* __restrict__ m,
                          const float* __restrict__ bias,
                          unsigned short* __restrict__ qo, unsigned short* __restrict__ mo,
                          float* __restrict__ bz) {
  int i = blockIdx.x * 256 + threadIdx.x;   // grid covers 4718592 + 4096 float4s
  if (i < 524288) {
    float4 v = ((const float4*)q)[i];
    ushort4 o; o.x = f2bf(v.x); o.y = f2bf(v.y); o.z = f2bf(v.z); o.w = f2bf(v.w);
    ((ushort4*)qo)[i] = o;
  } else if (i < 4718592) {
    int j = i - 524288;
    float4 v = ((const float4*)m)[j];
    ushort4 o; o.x = f2bf(v.x); o.y = f2bf(v.y); o.z = f2bf(v.z); o.w = f2bf(v.w);
    ((ushort4*)mo)[j] = o;
  } else {
    int j = i - 4718592;                   // < 4096: bias -> bias*log2e - 16
    float4 v = ((const float4*)bias)[j];
    float4 o;
    o.x = __builtin_fmaf(v.x, LOG2E, -16.f);
    o.y = __builtin_fmaf(v.y, LOG2E, -16.f);
    o.z = __builtin_fmaf(v.z, LOG2E, -16.f);
    o.w = __builtin_fmaf(v.w, LOG2E, -16.f);
    ((float4*)bz)[j] = o;
  }
}

// ---------- 1024x1024 transpose+convert for all 4 weights in one launch ----------
__global__ void transpose4(const float* __restrict__ Wq, const float* __restrict__ Wk,
                           const float* __restrict__ Wv, const float* __restrict__ Wo,
                           unsigned short* __restrict__ dst) {
  __shared__ float t[32][33];
  int z = blockIdx.z;
  const float* W = (z == 0) ? Wq : (z == 1) ? Wk : (z == 2) ? Wv : Wo;
  unsigned short* WT = dst + (size_t)z * 1048576;
  int bx = blockIdx.x * 32, by = blockIdx.y * 32;
  int x = threadIdx.x, y0 = threadIdx.y;
#pragma unroll
  for (int r = 0; r < 4; ++r)
    t[y0 + r * 8][x] = W[(size_t)(by + y0 + r * 8) * 1024 + bx + x];
  __syncthreads();
#pragma unroll
  for (int r = 0; r < 4; ++r)
    WT[(size_t)(bx + y0 + r * 8) * 1024 + by + x] = f2bf(t[x][y0 + r * 8]);
}

// ---------- fused K/V projection, plane-major LDS (conflict-free frags) -----
// LDS tile layout: plane p (k-octet) -> [128 rows][8 ushort]; fragment read =
// 16 consecutive 16B blocks (2-way bank alias = free).
__global__ __launch_bounds__(256, 2) void gemm_kv(
    const unsigned short* __restrict__ A,   // mbf [16384][1024]
    const unsigned short* __restrict__ Bk,  // WkT [1024][1024]
    const unsigned short* __restrict__ Bv,  // WvT [1024][1024]
    unsigned short* __restrict__ Kp,        // [16384][1024]
    unsigned short* __restrict__ Vt)        // [1024][16384]
{
  __shared__ __attribute__((aligned(16))) unsigned short lds[12288]; // A@0, Bk@4096, Bv@8192
  int w = threadIdx.x >> 6, lane = threadIdx.x & 63;
  int lh = lane & 15, q4 = lane >> 4;
  int id = blockIdx.x;
  int xcd = id & 7, j = id >> 3;
  int tm = (xcd * 16 + (j >> 3)) * 128;     // m-strip: 16 per XCD, n cycles inner
  int tn = (j & 7) * 128;
  int wm = (w & 1) * 64, wn = (w >> 1) * 64;

  f32x4 acck[4][4] = {}, accv[4][4] = {};

  for (int k0 = 0; k0 < 1024; k0 += 32) {
#pragma unroll
    for (int i = 0; i < 2; ++i) {
      int s = w * 2 + i;                    // seg 0..7: plane s>>1, row-half s&1
      int p = s >> 1, rh = s & 1;
      cp16(A  + (size_t)(tm + rh * 64 + lane) * 1024 + k0 + p * 8, lds + s * 512);
      cp16(Bk + (size_t)(tn + rh * 64 + lane) * 1024 + k0 + p * 8, lds + 4096 + s * 512);
      cp16(Bv + (size_t)(tn + rh * 64 + lane) * 1024 + k0 + p * 8, lds + 8192 + s * 512);
    }
    __syncthreads();
    bf16x8 afr[4], bkf[4], bvf[4];
#pragma unroll
    for (int r = 0; r < 4; ++r)
      afr[r] = *(const bf16x8*)(lds + q4 * 1024 + (wm + r * 16 + lh) * 8);
#pragma unroll
    for (int c = 0; c < 4; ++c) {
      bkf[c] = *(const bf16x8*)(lds + 4096 + q4 * 1024 + (wn + c * 16 + lh) * 8);
      bvf[c] = *(const bf16x8*)(lds + 8192 + q4 * 1024 + (wn + c * 16 + lh) * 8);
    }
#pragma unroll
    for (int r = 0; r < 4; ++r)
#pragma unroll
      for (int c = 0; c < 4; ++c) {
        acck[r][c] = MFMA32(afr[r], bkf[c], acck[r][c]);
        accv[r][c] = MFMA32(afr[r], bvf[c], accv[r][c]);
      }
    __syncthreads();
  }

#pragma unroll
  for (int r = 0; r < 4; ++r)
#pragma unroll
    for (int c = 0; c < 4; ++c) {
      int row = tm + wm + r * 16 + q4 * 4;   // +e = consecutive tokens
      int col = tn + wn + c * 16 + lh;
#pragma unroll
      for (int e = 0; e < 4; ++e)
        Kp[(size_t)(row + e) * 1024 + col] = f2bf(acck[r][c][e]);
      ushort4 v4;
      v4.x = f2bf(accv[r][c][0]); v4.y = f2bf(accv[r][c][1]);
      v4.z = f2bf(accv[r][c][2]); v4.w = f2bf(accv[r][c][3]);
      *(ushort4*)(Vt + (size_t)col * 16384 + row) = v4;   // consecutive tokens: 8B store
    }
}

// ---------- bf16 GEMM 64x64 tile, plane-major LDS (skinny grids) ------------
__global__ __launch_bounds__(256) void gemm64(
    const unsigned short* __restrict__ A, const unsigned short* __restrict__ B,
    float* __restrict__ Cf, unsigned short* __restrict__ Cb,
    int M, int N, int K, float scale)
{
  __shared__ __attribute__((aligned(16))) unsigned short lds[4096]; // A@0 (4 planes x 64 x 8), B@2048
  int w = threadIdx.x >> 6, lane = threadIdx.x & 63;
  int lh = lane & 15, q4 = lane >> 4;
  int tm = blockIdx.y * 64, tn = blockIdx.x * 64;
  int wm = (w & 1) * 32, wn = (w >> 1) * 32;

  f32x4 acc[2][2] = {};

  for (int k0 = 0; k0 < K; k0 += 32) {
    cp16(A + (size_t)(tm + lane) * K + k0 + w * 8, lds + w * 512);
    cp16(B + (size_t)(tn + lane) * K + k0 + w * 8, lds + 2048 + w * 512);
    __syncthreads();
    bf16x8 afr[2], bfr[2];
#pragma unroll
    for (int r = 0; r < 2; ++r)
      afr[r] = *(const bf16x8*)(lds + q4 * 512 + (wm + r * 16 + lh) * 8);
#pragma unroll
    for (int c = 0; c < 2; ++c)
      bfr[c] = *(const bf16x8*)(lds + 2048 + q4 * 512 + (wn + c * 16 + lh) * 8);
#pragma unroll
    for (int r = 0; r < 2; ++r)
#pragma unroll
      for (int c = 0; c < 2; ++c)
        acc[r][c] = MFMA32(afr[r], bfr[c], acc[r][c]);
    __syncthreads();
  }

#pragma unroll
  for (int r = 0; r < 2; ++r)
#pragma unroll
    for (int c = 0; c < 2; ++c)
#pragma unroll
      for (int e = 0; e < 4; ++e) {
        int row = tm + wm + r * 16 + q4 * 4 + e;
        int col = tn + wn + c * 16 + lh;
        if (Cb) Cb[(size_t)row * N + col] = f2bf(acc[r][c][e] * scale);
        else    Cf[(size_t)row * N + col] = acc[r][c][e] * scale;
      }
}

// ---------- attention v6: 64 q-rows per wave, double-buffered plane-major LDS
// Block = 2 waves (128 thr); wave owns 64 q (4 strips), full 64-token tile ->
// each K/V fragment feeds 2x the MFMA work of v4 (DS traffic halved).
// w0 stages K-tile, w1 stages V-tile (8 cp16 each) into the next buffer while
// computing the current one. po/lp interface unchanged (waves disjoint in q).
__global__ __launch_bounds__(128) void attn_kernel(
    const unsigned short* __restrict__ Q, const unsigned short* __restrict__ Kp,
    const unsigned short* __restrict__ VT, const float* __restrict__ bz,
    float* __restrict__ po, float* __restrict__ lp)
{
  __shared__ __attribute__((aligned(16))) unsigned short lds[16384]; // buf0: K@0,V@4096; buf1: @8192
  int w = threadIdx.x >> 6, lane = threadIdx.x & 63;
  int lh = lane & 15, q4 = lane >> 4;

  int id = blockIdx.x;
  int xcd = id & 7, j = id >> 3;
  int ql = j & 7;
  int half = ql & 1, qt = ql >> 1;
  int bh = (j >> 3) * 8 + xcd;
  int b = bh >> 4, h = bh & 15;
  int q0 = qt * 128;
  int t00 = half * 2048;

  const unsigned short* Qb = Q + (size_t)(b * 512 + q0 + w * 64) * 1024 + h * 64;
  const unsigned short* Kb = Kp + (size_t)(b * 4096) * 1024 + h * 64;
  const unsigned short* Vb = VT + (size_t)(h * 64) * 16384 + b * 4096;
  const float* bzg = bz + (size_t)b * 4096;

  // Q B-operand fragments: 4 strips of 16 q-rows
  bf16x8 bq[4][2];
#pragma unroll
  for (int s = 0; s < 4; ++s)
#pragma unroll
    for (int th = 0; th < 2; ++th)
      bq[s][th] = *(const bf16x8*)(Qb + (size_t)(s * 16 + lh) * 1024 + th * 32 + q4 * 8);

  f32x4 oa[4][4] = {};              // O^T accumulators [q-strip][d-tile]
  float ls[4] = {0.f, 0.f, 0.f, 0.f};

  // prologue: stage tile 0 into buf0 (K plane-major by d-octet, V by tok-octet)
  if (w == 0) {
#pragma unroll
    for (int s = 0; s < 8; ++s)
      cp16(Kb + (size_t)(t00 + lane) * 1024 + s * 8, lds + s * 512);
  } else {
#pragma unroll
    for (int s = 0; s < 8; ++s)
      cp16(Vb + (size_t)lane * 16384 + t00 + s * 8, lds + 4096 + s * 512);
  }

  for (int ti = 0; ti < 32; ++ti) {
    __syncthreads();                         // staged tile ti visible; buf[(ti+1)&1] free
    int cur = (ti & 1) * 8192;
    if (ti + 1 < 32) {
      int tn_ = t00 + (ti + 1) * 64;
      int nxt = ((ti + 1) & 1) * 8192;
      if (w == 0) {
#pragma unroll
        for (int s = 0; s < 8; ++s)
          cp16(Kb + (size_t)(tn_ + lane) * 1024 + s * 8, lds + nxt + s * 512);
      } else {
#pragma unroll
        for (int s = 0; s < 8; ++s)
          cp16(Vb + (size_t)lane * 16384 + tn_ + s * 8, lds + nxt + 4096 + s * 512);
      }
    }
    int t = t00 + ti * 64;
    const unsigned short* Kl = lds + cur;
    const unsigned short* Vl = lds + cur + 4096;

#pragma unroll
    for (int c = 0; c < 4; ++c) {            // 16-token subtiles
      bf16x8 kf0 = *(const bf16x8*)(Kl + (q4) * 512 + (c * 16 + lh) * 8);
      bf16x8 kf1 = *(const bf16x8*)(Kl + (4 + q4) * 512 + (c * 16 + lh) * 8);
      bf16x4 vf[4];
#pragma unroll
      for (int c2 = 0; c2 < 4; ++c2)
        vf[c2] = *(const bf16x4*)(Vl + (c * 2 + (q4 >> 1)) * 512 + (c2 * 16 + lh) * 8 + (q4 & 1) * 4);
      float4 b4 = *(const float4*)(bzg + t + c * 16 + q4 * 4);
      float bzf[4] = {b4.x, b4.y, b4.z, b4.w};
#pragma unroll
      for (int s = 0; s < 4; ++s) {
        f32x4 z = {};
        z = MFMA32(kf0, bq[s][0], z);
        z = MFMA32(kf1, bq[s][1], z);
        bf16x4 pb;
        float ps = 0.f;
#pragma unroll
        for (int e = 0; e < 4; ++e) {
          float p = __builtin_amdgcn_exp2f(z[e] + bzf[e]);
          ps += p;
          pb[e] = (short)f2bf(p);
        }
        ls[s] += ps;
#pragma unroll
        for (int c2 = 0; c2 < 4; ++c2)
          oa[s][c2] = MFMA16(vf[c2], pb, oa[s][c2]);
      }
    }
  }

  // l: lane holds partial for q = s*16+lh; reduce across the 4 q4 groups
#pragma unroll
  for (int s = 0; s < 4; ++s) {
    ls[s] += __shfl_xor(ls[s], 16);
    ls[s] += __shfl_xor(ls[s], 32);
  }

  // partial stores: po[half*256 + bh*4+qt][d=64][q=128]
  int sl = bh * 4 + qt;
  float* pslice = po + (size_t)(half * 256 + sl) * 8192;
#pragma unroll
  for (int s = 0; s < 4; ++s) {
    if (q4 == 0) lp[half * 32768 + sl * 128 + w * 64 + s * 16 + lh] = ls[s];
#pragma unroll
    for (int c2 = 0; c2 < 4; ++c2)
#pragma unroll
      for (int e = 0; e < 4; ++e)
        pslice[(c2 * 16 + q4 * 4 + e) * 128 + w * 64 + s * 16 + lh] = oa[s][c2][e];
  }
}

// ---------- merge token-half partials, normalize, pack to bf16 ao ----------
__global__ void norm_kernel(const float* __restrict__ po, const float* __restrict__ lp,
                            unsigned short* __restrict__ ao) {
  int g = blockIdx.x * 256 + threadIdx.x;   // 262144 threads
  int d8 = (g & 7) * 8;
  int rowid = g >> 3;                        // 0..32767 = bh*512 + qt*128 + qcol
  int bh = rowid >> 9, rq = rowid & 511, qt = rq >> 7, qcol = rq & 127;
  int sl = bh * 4 + qt;
  const float* p0 = po + (size_t)sl * 8192;
  const float* p1 = po + (size_t)(256 + sl) * 8192;
  float l = lp[sl * 128 + qcol] + lp[32768 + sl * 128 + qcol];
  float inv = 1.f / l;
  unsigned short o8[8];
#pragma unroll
  for (int k = 0; k < 8; ++k)
    o8[k] = f2bf((p0[(d8 + k) * 128 + qcol] + p1[(d8 + k) * 128 + qcol]) * inv);
  int b = bh >> 4, h = bh & 15;
  unsigned short* dst = ao + (size_t)(b * 512 + qt * 128 + qcol) * 1024 + h * 64 + d8;
  *(ushort4*)dst = *(ushort4*)o8;
  *(ushort4*)(dst + 4) = *(ushort4*)(o8 + 4);
}

// ---------- launch ----------
extern "C" void kernel_launch(void* const* d_in, const int* in_sizes, int n_in,
                              void* d_out, int out_size, void* d_ws, size_t ws_size,
                              hipStream_t stream) {
  const float* query  = (const float*)d_in[0];
  const float* memory = (const float*)d_in[1];
  const float* bias   = (const float*)d_in[2];
  const float* Wq     = (const float*)d_in[3];
  const float* Wk     = (const float*)d_in[4];
  const float* Wv     = (const float*)d_in[5];
  const float* Wo     = (const float*)d_in[6];
  float* out = (float*)d_out;

  unsigned short* ws  = (unsigned short*)d_ws;
  unsigned short* qbf = ws;                       // 2048*1024
  unsigned short* mbf = qbf + 2097152;            // 16384*1024
  unsigned short* WqT = mbf + 16777216;           // 4 x 1024*1024 contiguous
  unsigned short* WkT = WqT + 1048576;
  unsigned short* WvT = WkT + 1048576;
  unsigned short* WoT = WvT + 1048576;
  unsigned short* qp  = WoT + 1048576;            // 2048*1024 (scaled q proj)
  unsigned short* kp  = qp + 2097152;             // 16384*1024
  unsigned short* vT  = kp + 16777216;            // 1024*16384
  unsigned short* ao  = vT + 16777216;            // 2048*1024
  float* bzw = (float*)(ao + 2097152);            // 16384 floats (bias*log2e-16)
  // po/lp alias qbf+mbf (dead after the projection GEMMs)
  float* po = (float*)ws;                         // 512 slices x 8192 floats = 16 MB
  float* lp = po + 4194304;                       // 65536 floats

  conv_both<<<18448, 256, 0, stream>>>(query, memory, bias, qbf, mbf, bzw);
  transpose4<<<dim3(32, 32, 4), dim3(32, 8), 0, stream>>>(Wq, Wk, Wv, Wo, WqT);

  // q = (query@Wq) * (1/8)*log2e   [2048 x 1024]
  gemm64<<<dim3(16, 32), 256, 0, stream>>>(qbf, WqT, nullptr, qp, 2048, 1024, 1024, 0.125f * LOG2E);
  // fused: kp = memory@Wk, vT = (memory@Wv)^T
  gemm_kv<<<1024, 256, 0, stream>>>(mbf, WkT, WvT, kp, vT);

  attn_kernel<<<512, 128, 0, stream>>>(qp, kp, vT, bzw, po, lp);
  norm_kernel<<<1024, 256, 0, stream>>>(po, lp, ao);

  // out = ao @ Wo (fp32 out)
  gemm64<<<dim3(16, 32), 256, 0, stream>>>(ao, WoT, out, nullptr, 2048, 1024, 1024, 1.f);
}

// Round 7
// 305.964 us; speedup vs baseline: 1.2646x; 1.2646x over previous
//
#include <hip/hip_runtime.h>

// ---------- types ----------
typedef __attribute__((ext_vector_type(8))) short bf16x8;   // 8 bf16 in 4 VGPRs
typedef __attribute__((ext_vector_type(4))) short bf16x4;   // 4 bf16 in 2 VGPRs
typedef __attribute__((ext_vector_type(4))) float f32x4;    // MFMA C/D

#define MFMA32(a,b,c) __builtin_amdgcn_mfma_f32_16x16x32_bf16((a),(b),(c),0,0,0)
#define MFMA16(a,b,c) __builtin_amdgcn_mfma_f32_16x16x16bf16_1k((a),(b),(c),0,0,0)
#define LOG2E 1.44269504f

__device__ __forceinline__ unsigned short f2bf(float f) {
  unsigned int u = __float_as_uint(f);
  u += 0x7fffu + ((u >> 16) & 1u);      // round-to-nearest-even
  return (unsigned short)(u >> 16);
}

// async global->LDS, 16B per lane; LDS dest = wave-uniform base + lane*16
__device__ __forceinline__ void cp16(const void* g, void* l) {
  __builtin_amdgcn_global_load_lds((const __attribute__((address_space(1))) void*)g,
                                   (__attribute__((address_space(3))) void*)l, 16, 0, 0);
}

// ---------- fp32 -> bf16 (query, memory) + bias pre-transform, one launch ----
__global__ void conv_both(const float* __restrict__ q, const float* __restrict__ m,
                          const float* __restrict__ bias,
                          unsigned short* __restrict__ qo, unsigned short* __restrict__ mo,
                          float* __restrict__ bz) {
  int i = blockIdx.x * 256 + threadIdx.x;   // grid covers 4718592 + 4096 float4s
  if (i < 524288) {
    float4 v = ((const float4*)q)[i];
    ushort4 o; o.x = f2bf(v.x); o.y = f2bf(v.y); o.z = f2bf(v.z); o.w = f2bf(v.w);
    ((ushort4*)qo)[i] = o;
  } else if (i < 4718592) {
    int j = i - 524288;
    float4 v = ((const float4*)m)[j];
    ushort4 o; o.x = f2bf(v.x); o.y = f2bf(v.y); o.z = f2bf(v.z); o.w = f2bf(v.w);
    ((ushort4*)mo)[j] = o;
  } else {
    int j = i - 4718592;                   // < 4096: bias -> bias*log2e - 16
    float4 v = ((const float4*)bias)[j];
    float4 o;
    o.x = __builtin_fmaf(v.x, LOG2E, -16.f);
    o.y = __builtin_fmaf(v.y, LOG2E, -16.f);
    o.z = __builtin_fmaf(v.z, LOG2E, -16.f);
    o.w = __builtin_fmaf(v.w, LOG2E, -16.f);
    ((float4*)bz)[j] = o;
  }
}

// ---------- 1024x1024 transpose+convert for all 4 weights in one launch ----------
__global__ void transpose4(const float* __restrict__ Wq, const float* __restrict__ Wk,
                           const float* __restrict__ Wv, const float* __restrict__ Wo,
                           unsigned short* __restrict__ dst) {
  __shared__ float t[32][33];
  int z = blockIdx.z;
  const float* W = (z == 0) ? Wq : (z == 1) ? Wk : (z == 2) ? Wv : Wo;
  unsigned short* WT = dst + (size_t)z * 1048576;
  int bx = blockIdx.x * 32, by = blockIdx.y * 32;
  int x = threadIdx.x, y0 = threadIdx.y;
#pragma unroll
  for (int r = 0; r < 4; ++r)
    t[y0 + r * 8][x] = W[(size_t)(by + y0 + r * 8) * 1024 + bx + x];
  __syncthreads();
#pragma unroll
  for (int r = 0; r < 4; ++r)
    WT[(size_t)(bx + y0 + r * 8) * 1024 + by + x] = f2bf(t[x][y0 + r * 8]);
}

// ---------- fused K/V projection (round-5 staging) + LDS-coalesced Vt epilogue
// A-tile staged once, used for both weights: 32 MFMA per 3 staged tiles.
// XCD-swizzled grid: each XCD owns 16 contiguous m-strips; weights L2-resident.
__global__ __launch_bounds__(256, 2) void gemm_kv(
    const unsigned short* __restrict__ A,   // mbf [16384][1024]
    const unsigned short* __restrict__ Bk,  // WkT [1024][1024]
    const unsigned short* __restrict__ Bv,  // WvT [1024][1024]
    unsigned short* __restrict__ Kp,        // [16384][1024]
    unsigned short* __restrict__ Vt)        // [1024][16384]
{
  // staging: A@0, Bk@4096, Bv@8192 (ushorts). Epilogue reuses all 32 KB as
  // a [128 col][128 row] xor-swizzled Vt tile.
  __shared__ __attribute__((aligned(16))) unsigned short lds[16384];
  int w = threadIdx.x >> 6, lane = threadIdx.x & 63;
  int lh = lane & 15, q4 = lane >> 4;
  int id = blockIdx.x;
  int xcd = id & 7, j = id >> 3;
  int tm = (xcd * 16 + (j >> 3)) * 128;     // m-strip: 16 per XCD, n cycles inner
  int tn = (j & 7) * 128;
  int wm = (w & 1) * 64, wn = (w >> 1) * 64;

  f32x4 acck[4][4] = {}, accv[4][4] = {};

  for (int k0 = 0; k0 < 1024; k0 += 32) {
#pragma unroll
    for (int i = 0; i < 2; ++i) {
      int c = w * 2 + i;
      int o = c * 1024 + lane * 16;
      int row = o >> 6, colu = (o & 63) >> 1;
      cp16(A  + (size_t)(tm + row) * 1024 + k0 + colu, lds + c * 512);
      cp16(Bk + (size_t)(tn + row) * 1024 + k0 + colu, lds + 4096 + c * 512);
      cp16(Bv + (size_t)(tn + row) * 1024 + k0 + colu, lds + 8192 + c * 512);
    }
    __syncthreads();
    bf16x8 afr[4], bkf[4], bvf[4];
#pragma unroll
    for (int r = 0; r < 4; ++r)
      afr[r] = *(const bf16x8*)(lds + (wm + r * 16 + lh) * 32 + q4 * 8);
#pragma unroll
    for (int c = 0; c < 4; ++c) {
      bkf[c] = *(const bf16x8*)(lds + 4096 + (wn + c * 16 + lh) * 32 + q4 * 8);
      bvf[c] = *(const bf16x8*)(lds + 8192 + (wn + c * 16 + lh) * 32 + q4 * 8);
    }
#pragma unroll
    for (int r = 0; r < 4; ++r)
#pragma unroll
      for (int c = 0; c < 4; ++c) {
        acck[r][c] = MFMA32(afr[r], bkf[c], acck[r][c]);
        accv[r][c] = MFMA32(afr[r], bvf[c], accv[r][c]);
      }
    __syncthreads();
  }

  // Kp epilogue: row-major 2B stores coalesce within lh groups (verified r4: ~1x)
#pragma unroll
  for (int r = 0; r < 4; ++r)
#pragma unroll
    for (int c = 0; c < 4; ++c) {
      int row = tm + wm + r * 16 + q4 * 4;
      int col = tn + wn + c * 16 + lh;
#pragma unroll
      for (int e = 0; e < 4; ++e)
        Kp[(size_t)(row + e) * 1024 + col] = f2bf(acck[r][c][e]);
    }

  // Vt epilogue via LDS: write C-layout (xor-swizzled), read back coalesced.
#pragma unroll
  for (int r = 0; r < 4; ++r)
#pragma unroll
    for (int c = 0; c < 4; ++c) {
      int row = wm + r * 16 + q4 * 4;       // block-local m (+e consecutive)
      int col = wn + c * 16 + lh;           // block-local n
      ushort4 v4;
      v4.x = f2bf(accv[r][c][0]); v4.y = f2bf(accv[r][c][1]);
      v4.z = f2bf(accv[r][c][2]); v4.w = f2bf(accv[r][c][3]);
      *(ushort4*)(lds + col * 128 + (row ^ ((col & 15) << 3))) = v4;
    }
  __syncthreads();
#pragma unroll
  for (int pass = 0; pass < 8; ++pass) {
    int col = pass * 16 + (threadIdx.x >> 4);       // 0..127
    int jb = threadIdx.x & 15;                      // 8-row block
    const unsigned short* src = lds + col * 128 + ((jb ^ (col & 15)) << 3);
    *(int4*)(Vt + (size_t)(tn + col) * 16384 + tm + jb * 8) = *(const int4*)src;
  }
}

// ---------- bf16 GEMM 128x64 tile (q-proj, out-proj) ----------
__global__ __launch_bounds__(256) void gemm_bt64(
    const unsigned short* __restrict__ A, const unsigned short* __restrict__ B,
    float* __restrict__ Cf, unsigned short* __restrict__ Cb,
    int M, int N, int K, float scale)
{
  __shared__ __attribute__((aligned(16))) unsigned short lds[6144]; // A[128][32]@0, B[64][32]@4096
  int w = threadIdx.x >> 6, lane = threadIdx.x & 63;
  int lh = lane & 15, q4 = lane >> 4;
  int tm = blockIdx.y * 128, tn = blockIdx.x * 64;
  int wm = (w & 1) * 64, wn = (w >> 1) * 32;

  f32x4 acc[4][2] = {};

  for (int k0 = 0; k0 < K; k0 += 32) {
#pragma unroll
    for (int i = 0; i < 2; ++i) {
      int c = w * 2 + i;
      int o = c * 1024 + lane * 16;
      int row = o >> 6, colu = (o & 63) >> 1;
      cp16(A + (size_t)(tm + row) * K + k0 + colu, lds + c * 512);
    }
    {
      int o = w * 1024 + lane * 16;
      int row = o >> 6, colu = (o & 63) >> 1;
      cp16(B + (size_t)(tn + row) * K + k0 + colu, lds + 4096 + w * 512);
    }
    __syncthreads();
    bf16x8 afr[4], bfr[2];
#pragma unroll
    for (int r = 0; r < 4; ++r)
      afr[r] = *(const bf16x8*)(lds + (wm + r * 16 + lh) * 32 + q4 * 8);
#pragma unroll
    for (int c = 0; c < 2; ++c)
      bfr[c] = *(const bf16x8*)(lds + 4096 + (wn + c * 16 + lh) * 32 + q4 * 8);
#pragma unroll
    for (int r = 0; r < 4; ++r)
#pragma unroll
      for (int c = 0; c < 2; ++c)
        acc[r][c] = MFMA32(afr[r], bfr[c], acc[r][c]);
    __syncthreads();
  }

#pragma unroll
  for (int r = 0; r < 4; ++r)
#pragma unroll
    for (int c = 0; c < 2; ++c)
#pragma unroll
      for (int e = 0; e < 4; ++e) {
        int row = tm + wm + r * 16 + q4 * 4 + e;
        int col = tn + wn + c * 16 + lh;
        if (Cb) Cb[(size_t)row * N + col] = f2bf(acc[r][c][e] * scale);
        else    Cf[(size_t)row * N + col] = acc[r][c][e] * scale;
      }
}

// ---------- attention v4 (round-5 proven): LDS-staged K/V, register P -------
__global__ __launch_bounds__(256) void attn_kernel(
    const unsigned short* __restrict__ Q, const unsigned short* __restrict__ Kp,
    const unsigned short* __restrict__ VT, const float* __restrict__ bz,
    float* __restrict__ po, float* __restrict__ lp)
{
  __shared__ __attribute__((aligned(16))) unsigned short Klds[4096]; // [64 tok][8 blk of 8]
  __shared__ __attribute__((aligned(16))) unsigned short Vlds[4096]; // [64 d][8 blk of 8]
  int w = threadIdx.x >> 6, lane = threadIdx.x & 63;
  int lh = lane & 15, q4 = lane >> 4;

  // XCD swizzle: same-bh blocks land on same XCD (bh & 7 == xcd)
  int id = blockIdx.x;
  int xcd = id & 7, j = id >> 3;
  int ql = j & 7;                   // 8 blocks per bh
  int half = ql & 1, qt = ql >> 1;  // token half, q-tile
  int bh = (j >> 3) * 8 + xcd;
  int b = bh >> 4, h = bh & 15;
  int q0 = qt * 128;
  int t00 = half * 2048;

  const unsigned short* Qb = Q + (size_t)(b * 512 + q0 + w * 32) * 1024 + h * 64;
  const unsigned short* Kb = Kp + (size_t)(b * 4096) * 1024 + h * 64;
  const unsigned short* Vb = VT + (size_t)(h * 64) * 16384 + b * 4096;
  const float* bzg = bz + (size_t)b * 4096;

  // Q B-operand fragments: 2 strips of 16 q-rows
  bf16x8 bq[2][2];
#pragma unroll
  for (int s = 0; s < 2; ++s)
#pragma unroll
    for (int th = 0; th < 2; ++th)
      bq[s][th] = *(const bf16x8*)(Qb + (size_t)(s * 16 + lh) * 1024 + th * 32 + q4 * 8);

  f32x4 oa[2][4] = {};              // O^T accumulators [strip][d-tile]
  float ls[2] = {0.f, 0.f};

  int rl = lane >> 3, blk = lane & 7;
  int sw = ((blk ^ rl) * 8);        // xor-swizzled 8-ushort block offset in source row

  for (int ti = 0; ti < 32; ++ti) {
    int t = t00 + ti * 64;
    // ---- stage K[64 tok][64 d] and V^T[64 d][64 tok], xor-swizzled blocks ----
#pragma unroll
    for (int r = 0; r < 2; ++r) {
      int seg = r * 4 + w;
      int row = seg * 8 + rl;
      cp16(Kb + (size_t)(t + row) * 1024 + sw, Klds + seg * 512);
      cp16(Vb + (size_t)row * 16384 + t + sw, Vlds + seg * 512);
    }
    __syncthreads();

    // bias (pre-transformed) for this tile's tokens
    float4 bz4[4];
#pragma unroll
    for (int c = 0; c < 4; ++c)
      bz4[c] = *(const float4*)(bzg + t + c * 16 + q4 * 4);

    // K fragments: A[m=tok][k=d], lane m=lh, k=th*32+q4*8..+8
    bf16x8 kf[4][2];
#pragma unroll
    for (int c = 0; c < 4; ++c)
#pragma unroll
      for (int th = 0; th < 2; ++th)
        kf[c][th] = *(const bf16x8*)(Klds + (c * 16 + lh) * 64 + (((th << 2) + q4) ^ (lh & 7)) * 8);
    // V fragments: A[m=d][k=tok], lane m=lh (+c2*16), k=c*16+q4*4..+4
    bf16x4 vf[4][4];
#pragma unroll
    for (int c = 0; c < 4; ++c)
#pragma unroll
      for (int c2 = 0; c2 < 4; ++c2)
        vf[c][c2] = *(const bf16x4*)(Vlds + (c2 * 16 + lh) * 64 +
                                     (((c << 1) + (q4 >> 1)) ^ (lh & 7)) * 8 + (q4 & 1) * 4);

#pragma unroll
    for (int s = 0; s < 2; ++s) {
#pragma unroll
      for (int c = 0; c < 4; ++c) {
        f32x4 z = {};
        z = MFMA32(kf[c][0], bq[s][0], z);
        z = MFMA32(kf[c][1], bq[s][1], z);
        float bzf[4] = {bz4[c].x, bz4[c].y, bz4[c].z, bz4[c].w};
        bf16x4 pb;
        float ps = 0.f;
#pragma unroll
        for (int e = 0; e < 4; ++e) {
          float p = __builtin_amdgcn_exp2f(z[e] + bzf[e]);
          ps += p;
          pb[e] = (short)f2bf(p);
        }
        ls[s] += ps;
#pragma unroll
        for (int c2 = 0; c2 < 4; ++c2)
          oa[s][c2] = MFMA16(vf[c][c2], pb, oa[s][c2]);
      }
    }
    __syncthreads();
  }

  // l: lane holds partial for q=lh; reduce across the 4 q4 groups
#pragma unroll
  for (int s = 0; s < 2; ++s) {
    ls[s] += __shfl_xor(ls[s], 16);
    ls[s] += __shfl_xor(ls[s], 32);
  }

  // partial stores: po[half*256 + bh*4+qt][d=64][q=128]
  int sl = bh * 4 + qt;
  float* pslice = po + (size_t)(half * 256 + sl) * 8192;
#pragma unroll
  for (int s = 0; s < 2; ++s) {
    if (q4 == 0) lp[half * 32768 + sl * 128 + w * 32 + s * 16 + lh] = ls[s];
#pragma unroll
    for (int c2 = 0; c2 < 4; ++c2)
#pragma unroll
      for (int e = 0; e < 4; ++e)
        pslice[(c2 * 16 + q4 * 4 + e) * 128 + w * 32 + s * 16 + lh] = oa[s][c2][e];
  }
}

// ---------- merge token-half partials, normalize, pack to bf16 ao ----------
__global__ void norm_kernel(const float* __restrict__ po, const float* __restrict__ lp,
                            unsigned short* __restrict__ ao) {
  int g = blockIdx.x * 256 + threadIdx.x;   // 262144 threads
  int d8 = (g & 7) * 8;
  int rowid = g >> 3;                        // 0..32767 = bh*512 + qt*128 + qcol
  int bh = rowid >> 9, rq = rowid & 511, qt = rq >> 7, qcol = rq & 127;
  int sl = bh * 4 + qt;
  const float* p0 = po + (size_t)sl * 8192;
  const float* p1 = po + (size_t)(256 + sl) * 8192;
  float l = lp[sl * 128 + qcol] + lp[32768 + sl * 128 + qcol];
  float inv = 1.f / l;
  unsigned short o8[8];
#pragma unroll
  for (int k = 0; k < 8; ++k)
    o8[k] = f2bf((p0[(d8 + k) * 128 + qcol] + p1[(d8 + k) * 128 + qcol]) * inv);
  int b = bh >> 4, h = bh & 15;
  unsigned short* dst = ao + (size_t)(b * 512 + qt * 128 + qcol) * 1024 + h * 64 + d8;
  *(ushort4*)dst = *(ushort4*)o8;
  *(ushort4*)(dst + 4) = *(ushort4*)(o8 + 4);
}

// ---------- launch ----------
extern "C" void kernel_launch(void* const* d_in, const int* in_sizes, int n_in,
                              void* d_out, int out_size, void* d_ws, size_t ws_size,
                              hipStream_t stream) {
  const float* query  = (const float*)d_in[0];
  const float* memory = (const float*)d_in[1];
  const float* bias   = (const float*)d_in[2];
  const float* Wq     = (const float*)d_in[3];
  const float* Wk     = (const float*)d_in[4];
  const float* Wv     = (const float*)d_in[5];
  const float* Wo     = (const float*)d_in[6];
  float* out = (float*)d_out;

  unsigned short* ws  = (unsigned short*)d_ws;
  unsigned short* qbf = ws;                       // 2048*1024
  unsigned short* mbf = qbf + 2097152;            // 16384*1024
  unsigned short* WqT = mbf + 16777216;           // 4 x 1024*1024 contiguous
  unsigned short* WkT = WqT + 1048576;
  unsigned short* WvT = WkT + 1048576;
  unsigned short* WoT = WvT + 1048576;
  unsigned short* qp  = WoT + 1048576;            // 2048*1024 (scaled q proj)
  unsigned short* kp  = qp + 2097152;             // 16384*1024
  unsigned short* vT  = kp + 16777216;            // 1024*16384
  unsigned short* ao  = vT + 16777216;            // 2048*1024
  float* bzw = (float*)(ao + 2097152);            // 16384 floats (bias*log2e-16)
  // po/lp alias qbf+mbf (dead after the projection GEMMs)
  float* po = (float*)ws;                         // 512 slices x 8192 floats = 16 MB
  float* lp = po + 4194304;                       // 65536 floats

  conv_both<<<18448, 256, 0, stream>>>(query, memory, bias, qbf, mbf, bzw);
  transpose4<<<dim3(32, 32, 4), dim3(32, 8), 0, stream>>>(Wq, Wk, Wv, Wo, WqT);

  // q = (query@Wq) * (1/8)*log2e   [2048 x 1024]
  gemm_bt64<<<dim3(16, 16), 256, 0, stream>>>(qbf, WqT, nullptr, qp, 2048, 1024, 1024, 0.125f * LOG2E);
  // fused: kp = memory@Wk, vT = (memory@Wv)^T
  gemm_kv<<<1024, 256, 0, stream>>>(mbf, WkT, WvT, kp, vT);

  attn_kernel<<<512, 256, 0, stream>>>(qp, kp, vT, bzw, po, lp);
  norm_kernel<<<1024, 256, 0, stream>>>(po, lp, ao);

  // out = ao @ Wo (fp32 out)
  gemm_bt64<<<dim3(16, 16), 256, 0, stream>>>(ao, WoT, out, nullptr, 2048, 1024, 1024, 1.f);
}